// Round 4
// baseline (649.373 us; speedup 1.0000x reference)
//
#include <hip/hip_runtime.h>

typedef unsigned short u16;
typedef __bf16 bf16x8 __attribute__((ext_vector_type(8)));
typedef float f32x4 __attribute__((ext_vector_type(4)));

#define DEV static __device__ __forceinline__

constexpr int Bc  = 2;
constexpr int Lc  = 2048;
constexpr int Dc  = 2048;
constexpr int Hc  = 16;
constexpr int HDc = 128;
constexpr int Mc  = Bc * Lc;   // 4096
constexpr int N3c = 3 * Dc;    // 6144

DEV u16 f2bf(float f) {
  unsigned u = __builtin_bit_cast(unsigned, f);
  u += 0x7fffu + ((u >> 16) & 1u);
  return (u16)(u >> 16);
}
DEV float bf2f(u16 h) { return __builtin_bit_cast(float, ((unsigned)h) << 16); }

DEV void load16(const void* g, void* l) {
  __builtin_amdgcn_global_load_lds(
      (__attribute__((address_space(1))) void*)(g),
      (__attribute__((address_space(3))) void*)(l), 16, 0, 0);
}

// ---------------- fp32 -> bf16 straight convert ----------------
__global__ __launch_bounds__(256) void k_cvt(const float* __restrict__ src,
                                             u16* __restrict__ dst, int n8) {
  int i = blockIdx.x * 256 + threadIdx.x;
  if (i >= n8) return;
  const float4* s = (const float4*)src;
  float4 a = s[2 * i], b = s[2 * i + 1];
  uint4 o;
  o.x = f2bf(a.x) | ((unsigned)f2bf(a.y) << 16);
  o.y = f2bf(a.z) | ((unsigned)f2bf(a.w) << 16);
  o.z = f2bf(b.x) | ((unsigned)f2bf(b.y) << 16);
  o.w = f2bf(b.z) | ((unsigned)f2bf(b.w) << 16);
  ((uint4*)dst)[i] = o;
}

// ------- transpose + convert (weights): dst[c][r] (bf16) = src[r][c] (fp32) -------
__global__ __launch_bounds__(256) void k_tcvt(const float* __restrict__ src,
                                              u16* __restrict__ dst, int tiles_c,
                                              int R, long ss) {
  int tr = blockIdx.x / tiles_c, tc = blockIdx.x % tiles_c;
  const float* s = src + (long)tr * 128 * ss + tc * 128;
  u16* d = dst + (long)(tc * 128) * R + tr * 128;
  __shared__ u16 t[128 * 136];
  int tid = threadIdx.x;
#pragma unroll
  for (int p = 0; p < 16; p++) {
    int r = p * 8 + (tid >> 5);
    int c4 = (tid & 31) * 4;
    float4 v = *(const float4*)(s + (long)r * ss + c4);
    t[(c4 + 0) * 136 + r] = f2bf(v.x);
    t[(c4 + 1) * 136 + r] = f2bf(v.y);
    t[(c4 + 2) * 136 + r] = f2bf(v.z);
    t[(c4 + 3) * 136 + r] = f2bf(v.w);
  }
  __syncthreads();
#pragma unroll
  for (int p = 0; p < 8; p++) {
    int c = p * 16 + (tid >> 4);
    int r8 = (tid & 15) * 8;
    uint4 v = *(const uint4*)&t[c * 136 + r8];
    *(uint4*)(d + (long)c * R + r8) = v;
  }
}

// ------- bf16 V transpose: Vt[bh][d][l] = qkvb[b*L+l][4096 + h*128 + d] -------
__global__ __launch_bounds__(256) void k_vtrans(const u16* __restrict__ qkvb,
                                                u16* __restrict__ Vt) {
  int lt = blockIdx.x;   // 0..15 (tile over L)
  int bh = blockIdx.y;   // 0..31
  int b = bh >> 4, h = bh & 15;
  const u16* s = qkvb + (long)(b * Lc + lt * 128) * N3c + 2 * Dc + h * HDc;
  u16* d = Vt + (long)bh * HDc * Lc + lt * 128;
  __shared__ u16 t[128 * 136];
  int tid = threadIdx.x;
#pragma unroll
  for (int p = 0; p < 8; p++) {
    int r = p * 16 + (tid >> 4);
    int c = (tid & 15) * 8;
    uint4 v = *(const uint4*)(s + (long)r * N3c + c);
    const u16* pv = (const u16*)&v;
#pragma unroll
    for (int j = 0; j < 8; j++) t[(c + j) * 136 + r] = pv[j];
  }
  __syncthreads();
#pragma unroll
  for (int p = 0; p < 8; p++) {
    int c = p * 16 + (tid >> 4);
    int r8 = (tid & 15) * 8;
    *(uint4*)(d + (long)c * Lc + r8) = *(const uint4*)&t[c * 136 + r8];
  }
}

// ---------------- bf16 MFMA GEMM: C[M][N] = A[M][K] * Bt[N][K]^T ----------------
DEV void cstore(float* p, float v) { *p = v; }
DEV void cstore(u16* p, float v) { *p = f2bf(v); }

template <typename OT>
__global__ __launch_bounds__(256) void k_gemm(const u16* __restrict__ A,
                                              const u16* __restrict__ Bt,
                                              OT* __restrict__ C, int M, int N,
                                              int K) {
  __shared__ u16 sA[128 * 64], sB[128 * 64];
  int nb = N >> 7;
  int brow = blockIdx.x / nb, bcol = blockIdx.x % nb;
  int tid = threadIdx.x, w = tid >> 6, lane = tid & 63;
  int wr = w >> 1, wc = w & 1, quad = lane >> 4, l15 = lane & 15;
  int lr = lane >> 3, lc = lane & 7;
  const u16* Ab = A + ((long)(brow * 128 + w * 32 + lr)) * K + (lc ^ lr) * 8;
  const u16* Bb = Bt + ((long)(bcol * 128 + w * 32 + lr)) * K + (lc ^ lr) * 8;
  u16* sAw = sA + (w * 32) * 64;
  u16* sBw = sB + (w * 32) * 64;
  f32x4 acc[4][4] = {};
  for (int k0 = 0; k0 < K; k0 += 64) {
    __syncthreads();
#pragma unroll
    for (int i = 0; i < 4; i++) {
      load16(Ab + (long)i * 8 * K + k0, sAw + i * 8 * 64);
      load16(Bb + (long)i * 8 * K + k0, sBw + i * 8 * 64);
    }
    __syncthreads();
#pragma unroll
    for (int kk = 0; kk < 2; kk++) {
      bf16x8 af[4], bfr[4];
#pragma unroll
      for (int mi = 0; mi < 4; mi++) {
        int r = wr * 64 + mi * 16 + l15;
        af[mi] = *(const bf16x8*)&sA[r * 64 + (((kk * 4 + quad) ^ (r & 7)) << 3)];
      }
#pragma unroll
      for (int ni = 0; ni < 4; ni++) {
        int r = wc * 64 + ni * 16 + l15;
        bfr[ni] = *(const bf16x8*)&sB[r * 64 + (((kk * 4 + quad) ^ (r & 7)) << 3)];
      }
#pragma unroll
      for (int mi = 0; mi < 4; mi++)
#pragma unroll
        for (int ni = 0; ni < 4; ni++)
          acc[mi][ni] =
              __builtin_amdgcn_mfma_f32_16x16x32_bf16(af[mi], bfr[ni], acc[mi][ni], 0, 0, 0);
    }
  }
  long orow = (long)brow * 128 + wr * 64;
  int ocol = bcol * 128 + wc * 64;
#pragma unroll
  for (int mi = 0; mi < 4; mi++)
#pragma unroll
    for (int ni = 0; ni < 4; ni++)
#pragma unroll
      for (int r = 0; r < 4; r++)
        cstore(&C[(orow + mi * 16 + quad * 4 + r) * (long)N + ocol + ni * 16 + l15],
               acc[mi][ni][r]);
}

// ---------------- fused RMS-norm + RoPE (Q pre-scaled by 1/sqrt(HD)) ----------------
__global__ __launch_bounds__(256) void k_rmsrope(const u16* __restrict__ qkvb,
                                                 const float* __restrict__ pe,
                                                 const float* __restrict__ qsc,
                                                 const float* __restrict__ ksc,
                                                 u16* __restrict__ Qr,
                                                 u16* __restrict__ Kr) {
  int row = blockIdx.x;  // b*L + l
  int l = row & (Lc - 1);
  int b = row >> 11;
  int tid = threadIdx.x;
  int h = tid >> 4, s16 = tid & 15;
  int d0 = s16 * 8;
  const u16* qp = qkvb + (long)row * N3c + h * HDc + d0;
  uint4 qv = *(const uint4*)qp;
  uint4 kv = *(const uint4*)(qp + Dc);
  const u16* qu = (const u16*)&qv;
  const u16* ku = (const u16*)&kv;
  float q[8], k[8];
#pragma unroll
  for (int j = 0; j < 8; j++) {
    q[j] = bf2f(qu[j]);
    k[j] = bf2f(ku[j]);
  }
  float sq = 0.f, sk = 0.f;
#pragma unroll
  for (int j = 0; j < 8; j++) {
    sq += q[j] * q[j];
    sk += k[j] * k[j];
  }
#pragma unroll
  for (int m = 1; m < 16; m <<= 1) {
    sq += __shfl_xor(sq, m);
    sk += __shfl_xor(sk, m);
  }
  float rq = rsqrtf(sq * (1.f / HDc) + 1e-6f);
  float rk = rsqrtf(sk * (1.f / HDc) + 1e-6f);
  float qs8[8], ks8[8];
  *(float4*)&qs8[0] = *(const float4*)(qsc + d0);
  *(float4*)&qs8[4] = *(const float4*)(qsc + d0 + 4);
  *(float4*)&ks8[0] = *(const float4*)(ksc + d0);
  *(float4*)&ks8[4] = *(const float4*)(ksc + d0 + 4);
#pragma unroll
  for (int j = 0; j < 8; j++) {
    q[j] *= rq * qs8[j];
    k[j] *= rk * ks8[j];
  }
  float e[16];
  const float* pep = pe + (long)l * 256 + s16 * 16;
#pragma unroll
  for (int j = 0; j < 4; j++) *(float4*)&e[j * 4] = *(const float4*)(pep + j * 4);
  float qo[8], ko[8];
#pragma unroll
  for (int p = 0; p < 4; p++) {
    float e00 = e[p * 4 + 0], e01 = e[p * 4 + 1];
    float e10 = e[p * 4 + 2], e11 = e[p * 4 + 3];
    qo[2 * p]     = e00 * q[2 * p] + e01 * q[2 * p + 1];
    qo[2 * p + 1] = e10 * q[2 * p] + e11 * q[2 * p + 1];
    ko[2 * p]     = e00 * k[2 * p] + e01 * k[2 * p + 1];
    ko[2 * p + 1] = e10 * k[2 * p] + e11 * k[2 * p + 1];
  }
  constexpr float RS = 0.08838834764831845f;  // 1/sqrt(128)
  uint4 oq, ok;
  oq.x = f2bf(qo[0] * RS) | ((unsigned)f2bf(qo[1] * RS) << 16);
  oq.y = f2bf(qo[2] * RS) | ((unsigned)f2bf(qo[3] * RS) << 16);
  oq.z = f2bf(qo[4] * RS) | ((unsigned)f2bf(qo[5] * RS) << 16);
  oq.w = f2bf(qo[6] * RS) | ((unsigned)f2bf(qo[7] * RS) << 16);
  ok.x = f2bf(ko[0]) | ((unsigned)f2bf(ko[1]) << 16);
  ok.y = f2bf(ko[2]) | ((unsigned)f2bf(ko[3]) << 16);
  ok.z = f2bf(ko[4]) | ((unsigned)f2bf(ko[5]) << 16);
  ok.w = f2bf(ko[6]) | ((unsigned)f2bf(ko[7]) << 16);
  long o = (((long)(b * Hc + h)) * Lc + l) * HDc + d0;
  *(uint4*)(Qr + o) = oq;
  *(uint4*)(Kr + o) = ok;
}

// ---------------- flash attention v4: no swizzle, V direct from global, 24KB LDS ----
// Q frags in regs; K staged via lds-dma; V A-frags coalesced from global (V^T).
__global__ __launch_bounds__(256, 4) void k_attn(const u16* __restrict__ Qr,
                                                 const u16* __restrict__ Kr,
                                                 const u16* __restrict__ Vt,
                                                 u16* __restrict__ Ao) {
  __shared__ u16 smem[12288];  // 24 KB
  u16* sK = smem;              // [64][128] 16KB; epilogue: red [64][33] f32
  u16* sP = smem + 8192;       // [64][64]  8KB;  epilogue: rsum [64] f32
  int bx = blockIdx.x;
  int bh = bx >> 5, lt = bx & 31;
  const u16* Qg = Qr + ((long)bh * Lc + lt * 64) * HDc;
  const u16* Kg = Kr + (long)bh * Lc * HDc;
  const u16* Vg = Vt + (long)bh * HDc * Lc;
  int tid = threadIdx.x, w = tid >> 6, lane = tid & 63;
  int quad = lane >> 4, l15 = lane & 15;
  int wsl = w >> 1, wsm = w & 1;  // S-phase wave grid: l x m
  int wd = w >> 1, wl2 = w & 1;   // PV-phase wave grid: d x l

  // ---- Q fragments straight from global (A-frag layout is contiguous 16B) ----
  bf16x8 qf[2][4];
#pragma unroll
  for (int mi = 0; mi < 2; mi++) {
    int l = wsl * 32 + mi * 16 + l15;
#pragma unroll
    for (int kk = 0; kk < 4; kk++)
      qf[mi][kk] = *(const bf16x8*)(Qg + (long)l * HDc + (kk * 4 + quad) * 8);
  }

  f32x4 o[4][2] = {};
  float rs[8] = {};
  for (int t = 0; t < 32; t++) {
    int m0 = t * 64;
    __syncthreads();  // A: prev S reads of sK done, prev PV reads of sP done
    // stage K tile (lds-dma)
#pragma unroll
    for (int i = 0; i < 4; i++) {
      int r = i * 16 + w * 4 + quad;
      int gch = l15 ^ (r & 15);
      load16(Kg + ((long)(m0 + r)) * HDc + gch * 8, sK + (i * 16 + w * 4) * 128);
    }
    // V A-fragments direct from global (coalesced 64B row segments of V^T)
    bf16x8 av[4][2];
#pragma unroll
    for (int mi = 0; mi < 4; mi++) {
      int d = wd * 64 + mi * 16 + l15;
#pragma unroll
      for (int kk = 0; kk < 2; kk++)
        av[mi][kk] = *(const bf16x8*)(Vg + (long)d * Lc + m0 + (kk * 4 + quad) * 8);
    }
    __syncthreads();  // B: sK staged (drains av loads too)
    // S = Q K^T  (64 l x 64 m; per wave 32x32 -> mi2 x ni2)
    f32x4 s[2][2] = {};
#pragma unroll
    for (int kk = 0; kk < 4; kk++) {
      bf16x8 bk[2];
#pragma unroll
      for (int ni = 0; ni < 2; ni++) {
        int m = wsm * 32 + ni * 16 + l15;
        bk[ni] = *(const bf16x8*)&sK[m * 128 + (((kk * 4 + quad) ^ l15) << 3)];
      }
#pragma unroll
      for (int mi = 0; mi < 2; mi++)
#pragma unroll
        for (int ni = 0; ni < 2; ni++)
          s[mi][ni] =
              __builtin_amdgcn_mfma_f32_16x16x32_bf16(qf[mi][kk], bk[ni], s[mi][ni], 0, 0, 0);
    }
    // exp + pack P into sP[l][m] (swizzled, round-half-up bf16), accumulate row sums
#pragma unroll
    for (int mi = 0; mi < 2; mi++)
#pragma unroll
      for (int ni = 0; ni < 2; ni++) {
        int pc = wsm * 32 + ni * 16 + l15;
#pragma unroll
        for (int r = 0; r < 4; r++) {
          int pr = wsl * 32 + mi * 16 + quad * 4 + r;
          float p = __expf(s[mi][ni][r]);
          rs[mi * 4 + r] += p;
          unsigned u = __builtin_bit_cast(unsigned, p) + 0x8000u;
          sP[pr * 64 + ((((pc >> 3) ^ (pr & 7)) << 3) | (pc & 7))] = (u16)(u >> 16);
        }
      }
    __syncthreads();  // D: P visible
    // O^T += V^T P^T  (128 d x 64 l; per wave 64d x 32l -> mi4 x ni2)
#pragma unroll
    for (int kk = 0; kk < 2; kk++) {
      bf16x8 bp[2];
#pragma unroll
      for (int ni = 0; ni < 2; ni++) {
        int l = wl2 * 32 + ni * 16 + l15;
        bp[ni] = *(const bf16x8*)&sP[l * 64 + (((kk * 4 + quad) ^ (l & 7)) << 3)];
      }
#pragma unroll
      for (int mi = 0; mi < 4; mi++)
#pragma unroll
        for (int ni = 0; ni < 2; ni++)
          o[mi][ni] =
              __builtin_amdgcn_mfma_f32_16x16x32_bf16(av[mi][kk], bp[ni], o[mi][ni], 0, 0, 0);
    }
  }
  // ---- epilogue: reduce row sums, scale, store O (b64 packed) ----
  __syncthreads();
  float* red  = (float*)sK;  // [64][33] = 8448 B
  float* rsum = (float*)sP;  // [64]
#pragma unroll
  for (int mi = 0; mi < 2; mi++)
#pragma unroll
    for (int r = 0; r < 4; r++) {
      int l = wsl * 32 + mi * 16 + quad * 4 + r;
      red[l * 33 + wsm * 16 + l15] = rs[mi * 4 + r];
    }
  __syncthreads();
  if (tid < 64) {
    float a = 0.f;
#pragma unroll
    for (int j = 0; j < 32; j++) a += red[tid * 33 + j];
    rsum[tid] = a;
  }
  __syncthreads();
  int b = bh >> 4, h = bh & 15;
#pragma unroll
  for (int ni = 0; ni < 2; ni++) {
    int l = wl2 * 32 + ni * 16 + l15;
    float inv = 1.f / rsum[l];
    long rowb = ((long)(b * Lc + lt * 64 + l)) * Dc + h * HDc;
#pragma unroll
    for (int mi = 0; mi < 4; mi++) {
      int d = wd * 64 + mi * 16 + quad * 4;
      ushort4 pk;
      pk.x = f2bf(o[mi][ni][0] * inv);
      pk.y = f2bf(o[mi][ni][1] * inv);
      pk.z = f2bf(o[mi][ni][2] * inv);
      pk.w = f2bf(o[mi][ni][3] * inv);
      *(ushort4*)(Ao + rowb + d) = pk;
    }
  }
}

extern "C" void kernel_launch(void* const* d_in, const int* in_sizes, int n_in,
                              void* d_out, int out_size, void* d_ws, size_t ws_size,
                              hipStream_t stream) {
  const float* x      = (const float*)d_in[0];
  const float* pe     = (const float*)d_in[1];
  const float* w_qkv  = (const float*)d_in[2];
  const float* w_proj = (const float*)d_in[3];
  const float* qs     = (const float*)d_in[4];
  const float* ks     = (const float*)d_in[5];
  float* out = (float*)d_out;
  char* ws = (char*)d_ws;

  u16* xb    = (u16*)(ws);                  //  16.8 MB  x bf16 [4096][2048]
  u16* wqkvT = (u16*)(ws + 16777216);       //  25.2 MB  [6144][2048]
  u16* wpT   = (u16*)(ws + 41943040);       //   8.4 MB  [2048][2048]
  u16* qkvb  = (u16*)(ws + 50331648);       //  50.3 MB  [4096][6144] bf16
  u16* Qr    = (u16*)(ws + 100663296);      //  16.8 MB  [B][H][L][HD]
  u16* Kr    = (u16*)(ws + 117440512);      //  16.8 MB
  u16* Vtw   = (u16*)(ws + 134217728);      //  16.8 MB  [B][H][HD][L]
  u16* Ao    = (u16*)(ws + 150994944);      //  16.8 MB  [4096][2048] bf16

  k_cvt<<<4096, 256, 0, stream>>>(x, xb, Mc * Dc / 8);
  k_tcvt<<<16 * 48, 256, 0, stream>>>(w_qkv, wqkvT, 48, Dc, (long)N3c);
  k_tcvt<<<16 * 16, 256, 0, stream>>>(w_proj, wpT, 16, Dc, (long)Dc);
  k_gemm<u16><<<32 * 48, 256, 0, stream>>>(xb, wqkvT, qkvb, Mc, N3c, Dc);
  k_rmsrope<<<Mc, 256, 0, stream>>>(qkvb, pe, qs, ks, Qr, Kr);
  k_vtrans<<<dim3(16, 32), 256, 0, stream>>>(qkvb, Vtw);
  k_attn<<<32 * 32, 256, 0, stream>>>(Qr, Kr, Vtw, Ao);
  k_gemm<float><<<32 * 16, 256, 0, stream>>>(Ao, wpT, out, Mc, Dc, Dc);
}

// Round 5
// 524.912 us; speedup vs baseline: 1.2371x; 1.2371x over previous
//
#include <hip/hip_runtime.h>

typedef unsigned short u16;
typedef __bf16 bf16x8 __attribute__((ext_vector_type(8)));
typedef float f32x4 __attribute__((ext_vector_type(4)));

#define DEV static __device__ __forceinline__

constexpr int Bc  = 2;
constexpr int Lc  = 2048;
constexpr int Dc  = 2048;
constexpr int Hc  = 16;
constexpr int HDc = 128;
constexpr int Mc  = Bc * Lc;   // 4096
constexpr int N3c = 3 * Dc;    // 6144

DEV u16 f2bf(float f) {
  unsigned u = __builtin_bit_cast(unsigned, f);
  u += 0x7fffu + ((u >> 16) & 1u);
  return (u16)(u >> 16);
}
DEV float bf2f(u16 h) { return __builtin_bit_cast(float, ((unsigned)h) << 16); }

DEV void load16(const void* g, void* l) {
  __builtin_amdgcn_global_load_lds(
      (__attribute__((address_space(1))) void*)(g),
      (__attribute__((address_space(3))) void*)(l), 16, 0, 0);
}

// ---------------- fp32 -> bf16 straight convert ----------------
__global__ __launch_bounds__(256) void k_cvt(const float* __restrict__ src,
                                             u16* __restrict__ dst, int n8) {
  int i = blockIdx.x * 256 + threadIdx.x;
  if (i >= n8) return;
  const float4* s = (const float4*)src;
  float4 a = s[2 * i], b = s[2 * i + 1];
  uint4 o;
  o.x = f2bf(a.x) | ((unsigned)f2bf(a.y) << 16);
  o.y = f2bf(a.z) | ((unsigned)f2bf(a.w) << 16);
  o.z = f2bf(b.x) | ((unsigned)f2bf(b.y) << 16);
  o.w = f2bf(b.z) | ((unsigned)f2bf(b.w) << 16);
  ((uint4*)dst)[i] = o;
}

// ------- transpose + convert (weights): dst[c][r] (bf16) = src[r][c] (fp32) -------
__global__ __launch_bounds__(256) void k_tcvt(const float* __restrict__ src,
                                              u16* __restrict__ dst, int tiles_c,
                                              int R, long ss) {
  int tr = blockIdx.x / tiles_c, tc = blockIdx.x % tiles_c;
  const float* s = src + (long)tr * 128 * ss + tc * 128;
  u16* d = dst + (long)(tc * 128) * R + tr * 128;
  __shared__ u16 t[128 * 136];
  int tid = threadIdx.x;
#pragma unroll
  for (int p = 0; p < 16; p++) {
    int r = p * 8 + (tid >> 5);
    int c4 = (tid & 31) * 4;
    float4 v = *(const float4*)(s + (long)r * ss + c4);
    t[(c4 + 0) * 136 + r] = f2bf(v.x);
    t[(c4 + 1) * 136 + r] = f2bf(v.y);
    t[(c4 + 2) * 136 + r] = f2bf(v.z);
    t[(c4 + 3) * 136 + r] = f2bf(v.w);
  }
  __syncthreads();
#pragma unroll
  for (int p = 0; p < 8; p++) {
    int c = p * 16 + (tid >> 4);
    int r8 = (tid & 15) * 8;
    uint4 v = *(const uint4*)&t[c * 136 + r8];
    *(uint4*)(d + (long)c * R + r8) = v;
  }
}

// ------- bf16 V transpose: Vt[bh][d][l] = qkvb[b*L+l][4096 + h*128 + d] -------
__global__ __launch_bounds__(256) void k_vtrans(const u16* __restrict__ qkvb,
                                                u16* __restrict__ Vt) {
  int lt = blockIdx.x;   // 0..15 (tile over L)
  int bh = blockIdx.y;   // 0..31
  int b = bh >> 4, h = bh & 15;
  const u16* s = qkvb + (long)(b * Lc + lt * 128) * N3c + 2 * Dc + h * HDc;
  u16* d = Vt + (long)bh * HDc * Lc + lt * 128;
  __shared__ u16 t[128 * 136];
  int tid = threadIdx.x;
#pragma unroll
  for (int p = 0; p < 8; p++) {
    int r = p * 16 + (tid >> 4);
    int c = (tid & 15) * 8;
    uint4 v = *(const uint4*)(s + (long)r * N3c + c);
    const u16* pv = (const u16*)&v;
#pragma unroll
    for (int j = 0; j < 8; j++) t[(c + j) * 136 + r] = pv[j];
  }
  __syncthreads();
#pragma unroll
  for (int p = 0; p < 8; p++) {
    int c = p * 16 + (tid >> 4);
    int r8 = (tid & 15) * 8;
    *(uint4*)(d + (long)c * Lc + r8) = *(const uint4*)&t[c * 136 + r8];
  }
}

// ---------------- bf16 MFMA GEMM: C[M][N] = A[M][K] * Bt[N][K]^T ----------------
DEV void cstore(float* p, float v) { *p = v; }
DEV void cstore(u16* p, float v) { *p = f2bf(v); }

template <typename OT>
__global__ __launch_bounds__(256) void k_gemm(const u16* __restrict__ A,
                                              const u16* __restrict__ Bt,
                                              OT* __restrict__ C, int M, int N,
                                              int K) {
  __shared__ u16 sA[128 * 64], sB[128 * 64];
  int nb = N >> 7;
  int brow = blockIdx.x / nb, bcol = blockIdx.x % nb;
  int tid = threadIdx.x, w = tid >> 6, lane = tid & 63;
  int wr = w >> 1, wc = w & 1, quad = lane >> 4, l15 = lane & 15;
  int lr = lane >> 3, lc = lane & 7;
  const u16* Ab = A + ((long)(brow * 128 + w * 32 + lr)) * K + (lc ^ lr) * 8;
  const u16* Bb = Bt + ((long)(bcol * 128 + w * 32 + lr)) * K + (lc ^ lr) * 8;
  u16* sAw = sA + (w * 32) * 64;
  u16* sBw = sB + (w * 32) * 64;
  f32x4 acc[4][4] = {};
  for (int k0 = 0; k0 < K; k0 += 64) {
    __syncthreads();
#pragma unroll
    for (int i = 0; i < 4; i++) {
      load16(Ab + (long)i * 8 * K + k0, sAw + i * 8 * 64);
      load16(Bb + (long)i * 8 * K + k0, sBw + i * 8 * 64);
    }
    __syncthreads();
#pragma unroll
    for (int kk = 0; kk < 2; kk++) {
      bf16x8 af[4], bfr[4];
#pragma unroll
      for (int mi = 0; mi < 4; mi++) {
        int r = wr * 64 + mi * 16 + l15;
        af[mi] = *(const bf16x8*)&sA[r * 64 + (((kk * 4 + quad) ^ (r & 7)) << 3)];
      }
#pragma unroll
      for (int ni = 0; ni < 4; ni++) {
        int r = wc * 64 + ni * 16 + l15;
        bfr[ni] = *(const bf16x8*)&sB[r * 64 + (((kk * 4 + quad) ^ (r & 7)) << 3)];
      }
#pragma unroll
      for (int mi = 0; mi < 4; mi++)
#pragma unroll
        for (int ni = 0; ni < 4; ni++)
          acc[mi][ni] =
              __builtin_amdgcn_mfma_f32_16x16x32_bf16(af[mi], bfr[ni], acc[mi][ni], 0, 0, 0);
    }
  }
  long orow = (long)brow * 128 + wr * 64;
  int ocol = bcol * 128 + wc * 64;
#pragma unroll
  for (int mi = 0; mi < 4; mi++)
#pragma unroll
    for (int ni = 0; ni < 4; ni++)
#pragma unroll
      for (int r = 0; r < 4; r++)
        cstore(&C[(orow + mi * 16 + quad * 4 + r) * (long)N + ocol + ni * 16 + l15],
               acc[mi][ni][r]);
}

// ---------------- fused RMS-norm + RoPE (Q pre-scaled by 1/sqrt(HD)) ----------------
__global__ __launch_bounds__(256) void k_rmsrope(const u16* __restrict__ qkvb,
                                                 const float* __restrict__ pe,
                                                 const float* __restrict__ qsc,
                                                 const float* __restrict__ ksc,
                                                 u16* __restrict__ Qr,
                                                 u16* __restrict__ Kr) {
  int row = blockIdx.x;  // b*L + l
  int l = row & (Lc - 1);
  int b = row >> 11;
  int tid = threadIdx.x;
  int h = tid >> 4, s16 = tid & 15;
  int d0 = s16 * 8;
  const u16* qp = qkvb + (long)row * N3c + h * HDc + d0;
  uint4 qv = *(const uint4*)qp;
  uint4 kv = *(const uint4*)(qp + Dc);
  const u16* qu = (const u16*)&qv;
  const u16* ku = (const u16*)&kv;
  float q[8], k[8];
#pragma unroll
  for (int j = 0; j < 8; j++) {
    q[j] = bf2f(qu[j]);
    k[j] = bf2f(ku[j]);
  }
  float sq = 0.f, sk = 0.f;
#pragma unroll
  for (int j = 0; j < 8; j++) {
    sq += q[j] * q[j];
    sk += k[j] * k[j];
  }
#pragma unroll
  for (int m = 1; m < 16; m <<= 1) {
    sq += __shfl_xor(sq, m);
    sk += __shfl_xor(sk, m);
  }
  float rq = rsqrtf(sq * (1.f / HDc) + 1e-6f);
  float rk = rsqrtf(sk * (1.f / HDc) + 1e-6f);
  float qs8[8], ks8[8];
  *(float4*)&qs8[0] = *(const float4*)(qsc + d0);
  *(float4*)&qs8[4] = *(const float4*)(qsc + d0 + 4);
  *(float4*)&ks8[0] = *(const float4*)(ksc + d0);
  *(float4*)&ks8[4] = *(const float4*)(ksc + d0 + 4);
#pragma unroll
  for (int j = 0; j < 8; j++) {
    q[j] *= rq * qs8[j];
    k[j] *= rk * ks8[j];
  }
  float e[16];
  const float* pep = pe + (long)l * 256 + s16 * 16;
#pragma unroll
  for (int j = 0; j < 4; j++) *(float4*)&e[j * 4] = *(const float4*)(pep + j * 4);
  float qo[8], ko[8];
#pragma unroll
  for (int p = 0; p < 4; p++) {
    float e00 = e[p * 4 + 0], e01 = e[p * 4 + 1];
    float e10 = e[p * 4 + 2], e11 = e[p * 4 + 3];
    qo[2 * p]     = e00 * q[2 * p] + e01 * q[2 * p + 1];
    qo[2 * p + 1] = e10 * q[2 * p] + e11 * q[2 * p + 1];
    ko[2 * p]     = e00 * k[2 * p] + e01 * k[2 * p + 1];
    ko[2 * p + 1] = e10 * k[2 * p] + e11 * k[2 * p + 1];
  }
  constexpr float RS = 0.08838834764831845f;  // 1/sqrt(128)
  uint4 oq, ok;
  oq.x = f2bf(qo[0] * RS) | ((unsigned)f2bf(qo[1] * RS) << 16);
  oq.y = f2bf(qo[2] * RS) | ((unsigned)f2bf(qo[3] * RS) << 16);
  oq.z = f2bf(qo[4] * RS) | ((unsigned)f2bf(qo[5] * RS) << 16);
  oq.w = f2bf(qo[6] * RS) | ((unsigned)f2bf(qo[7] * RS) << 16);
  ok.x = f2bf(ko[0]) | ((unsigned)f2bf(ko[1]) << 16);
  ok.y = f2bf(ko[2]) | ((unsigned)f2bf(ko[3]) << 16);
  ok.z = f2bf(ko[4]) | ((unsigned)f2bf(ko[5]) << 16);
  ok.w = f2bf(ko[6]) | ((unsigned)f2bf(ko[7]) << 16);
  long o = (((long)(b * Hc + h)) * Lc + l) * HDc + d0;
  *(uint4*)(Qr + o) = oq;
  *(uint4*)(Kr + o) = ok;
}

// ---------------- flash attention v5: Q in regs, K/V via lds-dma, 40KB, no swizzle ----
__global__ __launch_bounds__(256, 4) void k_attn(const u16* __restrict__ Qr,
                                                 const u16* __restrict__ Kr,
                                                 const u16* __restrict__ Vt,
                                                 u16* __restrict__ Ao) {
  __shared__ u16 smem[20480];  // 40 KB
  u16* sK = smem;              // [64][128] 16KB; epilogue: red
  u16* sV = smem + 8192;       // [128][64] 16KB; epilogue: rsum
  u16* sP = smem + 16384;      // [64][64]  8KB
  int bx = blockIdx.x;
  int bh = bx >> 5, lt = bx & 31;
  const u16* Qg = Qr + ((long)bh * Lc + lt * 64) * HDc;
  const u16* Kg = Kr + (long)bh * Lc * HDc;
  const u16* Vg = Vt + (long)bh * HDc * Lc;
  int tid = threadIdx.x, w = tid >> 6, lane = tid & 63;
  int quad = lane >> 4, l15 = lane & 15;
  int wsl = w >> 1, wsm = w & 1;  // S-phase wave grid: l x m
  int wd = w >> 1, wl2 = w & 1;   // PV-phase wave grid: d x l

  // ---- Q fragments straight from global (A-frag layout is contiguous 16B) ----
  bf16x8 qf[2][4];
#pragma unroll
  for (int mi = 0; mi < 2; mi++) {
    int l = wsl * 32 + mi * 16 + l15;
#pragma unroll
    for (int kk = 0; kk < 4; kk++)
      qf[mi][kk] = *(const bf16x8*)(Qg + (long)l * HDc + (kk * 4 + quad) * 8);
  }

  f32x4 o[4][2] = {};
  float rs[8] = {};
  for (int t = 0; t < 32; t++) {
    int m0 = t * 64;
    __syncthreads();  // A: prev PV done reading sP/sV
#pragma unroll
    for (int i = 0; i < 4; i++) {
      int r = i * 16 + w * 4 + quad;
      int gch = l15 ^ (r & 15);
      load16(Kg + ((long)(m0 + r)) * HDc + gch * 8, sK + (i * 16 + w * 4) * 128);
    }
#pragma unroll
    for (int i = 0; i < 4; i++) {
      int r = i * 32 + w * 8 + (lane >> 3);
      int gch = (lane & 7) ^ (r & 7);
      load16(Vg + (long)r * Lc + m0 + gch * 8, sV + (i * 32 + w * 8) * 64);
    }
    __syncthreads();  // B: staged
    // S = Q K^T  (64 l x 64 m; per wave 32x32 -> mi2 x ni2)
    f32x4 s[2][2] = {};
#pragma unroll
    for (int kk = 0; kk < 4; kk++) {
      bf16x8 bk[2];
#pragma unroll
      for (int ni = 0; ni < 2; ni++) {
        int m = wsm * 32 + ni * 16 + l15;
        bk[ni] = *(const bf16x8*)&sK[m * 128 + (((kk * 4 + quad) ^ l15) << 3)];
      }
#pragma unroll
      for (int mi = 0; mi < 2; mi++)
#pragma unroll
        for (int ni = 0; ni < 2; ni++)
          s[mi][ni] =
              __builtin_amdgcn_mfma_f32_16x16x32_bf16(qf[mi][kk], bk[ni], s[mi][ni], 0, 0, 0);
    }
    // exp + pack P into sP[l][m] (swizzled, round-half-up bf16), accumulate row sums
#pragma unroll
    for (int mi = 0; mi < 2; mi++)
#pragma unroll
      for (int ni = 0; ni < 2; ni++) {
        int pc = wsm * 32 + ni * 16 + l15;
#pragma unroll
        for (int r = 0; r < 4; r++) {
          int pr = wsl * 32 + mi * 16 + quad * 4 + r;
          float p = __expf(s[mi][ni][r]);
          rs[mi * 4 + r] += p;
          unsigned u = __builtin_bit_cast(unsigned, p) + 0x8000u;
          sP[pr * 64 + ((((pc >> 3) ^ (pr & 7)) << 3) | (pc & 7))] = (u16)(u >> 16);
        }
      }
    __syncthreads();  // D: P visible
    // O^T += V^T P^T  (128 d x 64 l; per wave 64d x 32l -> mi4 x ni2)
#pragma unroll
    for (int kk = 0; kk < 2; kk++) {
      bf16x8 av[4], bp[2];
#pragma unroll
      for (int mi = 0; mi < 4; mi++) {
        int d = wd * 64 + mi * 16 + l15;
        av[mi] = *(const bf16x8*)&sV[d * 64 + (((kk * 4 + quad) ^ (d & 7)) << 3)];
      }
#pragma unroll
      for (int ni = 0; ni < 2; ni++) {
        int l = wl2 * 32 + ni * 16 + l15;
        bp[ni] = *(const bf16x8*)&sP[l * 64 + (((kk * 4 + quad) ^ (l & 7)) << 3)];
      }
#pragma unroll
      for (int mi = 0; mi < 4; mi++)
#pragma unroll
        for (int ni = 0; ni < 2; ni++)
          o[mi][ni] =
              __builtin_amdgcn_mfma_f32_16x16x32_bf16(av[mi], bp[ni], o[mi][ni], 0, 0, 0);
    }
  }
  // ---- epilogue: reduce row sums, scale, store O (b64 packed) ----
  __syncthreads();
  float* red  = (float*)sK;  // [64][33]
  float* rsum = (float*)sV;  // [64]
#pragma unroll
  for (int mi = 0; mi < 2; mi++)
#pragma unroll
    for (int r = 0; r < 4; r++) {
      int l = wsl * 32 + mi * 16 + quad * 4 + r;
      red[l * 33 + wsm * 16 + l15] = rs[mi * 4 + r];
    }
  __syncthreads();
  if (tid < 64) {
    float a = 0.f;
#pragma unroll
    for (int j = 0; j < 32; j++) a += red[tid * 33 + j];
    rsum[tid] = a;
  }
  __syncthreads();
  int b = bh >> 4, h = bh & 15;
#pragma unroll
  for (int ni = 0; ni < 2; ni++) {
    int l = wl2 * 32 + ni * 16 + l15;
    float inv = 1.f / rsum[l];
    long rowb = ((long)(b * Lc + lt * 64 + l)) * Dc + h * HDc;
#pragma unroll
    for (int mi = 0; mi < 4; mi++) {
      int d = wd * 64 + mi * 16 + quad * 4;
      ushort4 pk;
      pk.x = f2bf(o[mi][ni][0] * inv);
      pk.y = f2bf(o[mi][ni][1] * inv);
      pk.z = f2bf(o[mi][ni][2] * inv);
      pk.w = f2bf(o[mi][ni][3] * inv);
      *(ushort4*)(Ao + rowb + d) = pk;
    }
  }
}

extern "C" void kernel_launch(void* const* d_in, const int* in_sizes, int n_in,
                              void* d_out, int out_size, void* d_ws, size_t ws_size,
                              hipStream_t stream) {
  const float* x      = (const float*)d_in[0];
  const float* pe     = (const float*)d_in[1];
  const float* w_qkv  = (const float*)d_in[2];
  const float* w_proj = (const float*)d_in[3];
  const float* qs     = (const float*)d_in[4];
  const float* ks     = (const float*)d_in[5];
  float* out = (float*)d_out;
  char* ws = (char*)d_ws;

  u16* xb    = (u16*)(ws);                  //  16.8 MB  x bf16 [4096][2048]
  u16* wqkvT = (u16*)(ws + 16777216);       //  25.2 MB  [6144][2048]
  u16* wpT   = (u16*)(ws + 41943040);       //   8.4 MB  [2048][2048]
  u16* qkvb  = (u16*)(ws + 50331648);       //  50.3 MB  [4096][6144] bf16
  u16* Qr    = (u16*)(ws + 100663296);      //  16.8 MB  [B][H][L][HD]
  u16* Kr    = (u16*)(ws + 117440512);      //  16.8 MB
  u16* Vtw   = (u16*)(ws + 134217728);      //  16.8 MB  [B][H][HD][L]
  u16* Ao    = (u16*)(ws + 150994944);      //  16.8 MB  [4096][2048] bf16

  k_cvt<<<4096, 256, 0, stream>>>(x, xb, Mc * Dc / 8);
  k_tcvt<<<16 * 48, 256, 0, stream>>>(w_qkv, wqkvT, 48, Dc, (long)N3c);
  k_tcvt<<<16 * 16, 256, 0, stream>>>(w_proj, wpT, 16, Dc, (long)Dc);
  k_gemm<u16><<<32 * 48, 256, 0, stream>>>(xb, wqkvT, qkvb, Mc, N3c, Dc);
  k_rmsrope<<<Mc, 256, 0, stream>>>(qkvb, pe, qs, ks, Qr, Kr);
  k_vtrans<<<dim3(16, 32), 256, 0, stream>>>(qkvb, Vtw);
  k_attn<<<32 * 32, 256, 0, stream>>>(Qr, Kr, Vtw, Ao);
  k_gemm<float><<<32 * 16, 256, 0, stream>>>(Ao, wpT, out, Mc, Dc, Dc);
}

// Round 6
// 426.821 us; speedup vs baseline: 1.5214x; 1.2298x over previous
//
#include <hip/hip_runtime.h>

typedef unsigned short u16;
typedef __bf16 bf16x8 __attribute__((ext_vector_type(8)));
typedef float f32x4 __attribute__((ext_vector_type(4)));

#define DEV static __device__ __forceinline__

constexpr int Bc  = 2;
constexpr int Lc  = 2048;
constexpr int Dc  = 2048;
constexpr int Hc  = 16;
constexpr int HDc = 128;
constexpr int Mc  = Bc * Lc;   // 4096
constexpr int N3c = 3 * Dc;    // 6144

DEV u16 f2bf(float f) {
  unsigned u = __builtin_bit_cast(unsigned, f);
  u += 0x7fffu + ((u >> 16) & 1u);
  return (u16)(u >> 16);
}
DEV float bf2f(u16 h) { return __builtin_bit_cast(float, ((unsigned)h) << 16); }

DEV void load16(const void* g, void* l) {
  __builtin_amdgcn_global_load_lds(
      (__attribute__((address_space(1))) void*)(g),
      (__attribute__((address_space(3))) void*)(l), 16, 0, 0);
}

// ---------------- merged prep: x->bf16 convert + both weight transposes ----------------
// grid: [0,4096) cvt of x ; [4096,4864) tcvt w_qkv ; [4864,5120) tcvt w_proj
__global__ __launch_bounds__(256) void k_prep(const float* __restrict__ x,
                                              const float* __restrict__ w_qkv,
                                              const float* __restrict__ w_proj,
                                              u16* __restrict__ xb,
                                              u16* __restrict__ wqkvT,
                                              u16* __restrict__ wpT) {
  __shared__ u16 t[128 * 136];
  int bid = blockIdx.x;
  int tid = threadIdx.x;
  if (bid < 4096) {
    int i = bid * 256 + tid;
    const float4* s = (const float4*)x;
    float4 a = s[2 * i], b = s[2 * i + 1];
    uint4 o;
    o.x = f2bf(a.x) | ((unsigned)f2bf(a.y) << 16);
    o.y = f2bf(a.z) | ((unsigned)f2bf(a.w) << 16);
    o.z = f2bf(b.x) | ((unsigned)f2bf(b.y) << 16);
    o.w = f2bf(b.z) | ((unsigned)f2bf(b.w) << 16);
    ((uint4*)xb)[i] = o;
    return;
  }
  const float* src;
  u16* dst;
  int tiles_c;
  long ss;
  if (bid < 4096 + 768) {
    int bx = bid - 4096;
    src = w_qkv; dst = wqkvT; tiles_c = 48; ss = N3c;
    int tr = bx / tiles_c, tc = bx % tiles_c;
    src += (long)tr * 128 * ss + tc * 128;
    dst += (long)(tc * 128) * Dc + tr * 128;
  } else {
    int bx = bid - 4864;
    src = w_proj; dst = wpT; tiles_c = 16; ss = Dc;
    int tr = bx / tiles_c, tc = bx % tiles_c;
    src += (long)tr * 128 * ss + tc * 128;
    dst += (long)(tc * 128) * Dc + tr * 128;
  }
#pragma unroll
  for (int p = 0; p < 16; p++) {
    int r = p * 8 + (tid >> 5);
    int c4 = (tid & 31) * 4;
    float4 v = *(const float4*)(src + (long)r * ss + c4);
    t[(c4 + 0) * 136 + r] = f2bf(v.x);
    t[(c4 + 1) * 136 + r] = f2bf(v.y);
    t[(c4 + 2) * 136 + r] = f2bf(v.z);
    t[(c4 + 3) * 136 + r] = f2bf(v.w);
  }
  __syncthreads();
#pragma unroll
  for (int p = 0; p < 8; p++) {
    int c = p * 16 + (tid >> 4);
    int r8 = (tid & 15) * 8;
    uint4 v = *(const uint4*)&t[c * 136 + r8];
    *(uint4*)(dst + (long)c * Dc + r8) = v;
  }
}

// ------- bf16 V transpose: Vt[bh][d][l] = qkvb[b*L+l][4096 + h*128 + d] -------
__global__ __launch_bounds__(256) void k_vtrans(const u16* __restrict__ qkvb,
                                                u16* __restrict__ Vt) {
  int lt = blockIdx.x;   // 0..15 (tile over L)
  int bh = blockIdx.y;   // 0..31
  int b = bh >> 4, h = bh & 15;
  const u16* s = qkvb + (long)(b * Lc + lt * 128) * N3c + 2 * Dc + h * HDc;
  u16* d = Vt + (long)bh * HDc * Lc + lt * 128;
  __shared__ u16 t[128 * 136];
  int tid = threadIdx.x;
#pragma unroll
  for (int p = 0; p < 8; p++) {
    int r = p * 16 + (tid >> 4);
    int c = (tid & 15) * 8;
    uint4 v = *(const uint4*)(s + (long)r * N3c + c);
    const u16* pv = (const u16*)&v;
#pragma unroll
    for (int j = 0; j < 8; j++) t[(c + j) * 136 + r] = pv[j];
  }
  __syncthreads();
#pragma unroll
  for (int p = 0; p < 8; p++) {
    int c = p * 16 + (tid >> 4);
    int r8 = (tid & 15) * 8;
    *(uint4*)(d + (long)c * Lc + r8) = *(const uint4*)&t[c * 136 + r8];
  }
}

// ---------------- bf16 MFMA GEMM: C[M][N] = A[M][K] * Bt[N][K]^T ----------------
DEV void cstore(float* p, float v) { *p = v; }
DEV void cstore(u16* p, float v) { *p = f2bf(v); }

template <typename OT>
__global__ __launch_bounds__(256) void k_gemm(const u16* __restrict__ A,
                                              const u16* __restrict__ Bt,
                                              OT* __restrict__ C, int M, int N,
                                              int K) {
  __shared__ u16 sA[128 * 64], sB[128 * 64];
  int nb = N >> 7;
  int brow = blockIdx.x / nb, bcol = blockIdx.x % nb;
  int tid = threadIdx.x, w = tid >> 6, lane = tid & 63;
  int wr = w >> 1, wc = w & 1, quad = lane >> 4, l15 = lane & 15;
  int lr = lane >> 3, lc = lane & 7;
  const u16* Ab = A + ((long)(brow * 128 + w * 32 + lr)) * K + (lc ^ lr) * 8;
  const u16* Bb = Bt + ((long)(bcol * 128 + w * 32 + lr)) * K + (lc ^ lr) * 8;
  u16* sAw = sA + (w * 32) * 64;
  u16* sBw = sB + (w * 32) * 64;
  f32x4 acc[4][4] = {};
  for (int k0 = 0; k0 < K; k0 += 64) {
    __syncthreads();
#pragma unroll
    for (int i = 0; i < 4; i++) {
      load16(Ab + (long)i * 8 * K + k0, sAw + i * 8 * 64);
      load16(Bb + (long)i * 8 * K + k0, sBw + i * 8 * 64);
    }
    __syncthreads();
#pragma unroll
    for (int kk = 0; kk < 2; kk++) {
      bf16x8 af[4], bfr[4];
#pragma unroll
      for (int mi = 0; mi < 4; mi++) {
        int r = wr * 64 + mi * 16 + l15;
        af[mi] = *(const bf16x8*)&sA[r * 64 + (((kk * 4 + quad) ^ (r & 7)) << 3)];
      }
#pragma unroll
      for (int ni = 0; ni < 4; ni++) {
        int r = wc * 64 + ni * 16 + l15;
        bfr[ni] = *(const bf16x8*)&sB[r * 64 + (((kk * 4 + quad) ^ (r & 7)) << 3)];
      }
#pragma unroll
      for (int mi = 0; mi < 4; mi++)
#pragma unroll
        for (int ni = 0; ni < 4; ni++)
          acc[mi][ni] =
              __builtin_amdgcn_mfma_f32_16x16x32_bf16(af[mi], bfr[ni], acc[mi][ni], 0, 0, 0);
    }
  }
  long orow = (long)brow * 128 + wr * 64;
  int ocol = bcol * 128 + wc * 64;
#pragma unroll
  for (int mi = 0; mi < 4; mi++)
#pragma unroll
    for (int ni = 0; ni < 4; ni++)
#pragma unroll
      for (int r = 0; r < 4; r++)
        cstore(&C[(orow + mi * 16 + quad * 4 + r) * (long)N + ocol + ni * 16 + l15],
               acc[mi][ni][r]);
}

// ---------------- fused RMS-norm + RoPE (Q pre-scaled by 1/sqrt(HD)) ----------------
__global__ __launch_bounds__(256) void k_rmsrope(const u16* __restrict__ qkvb,
                                                 const float* __restrict__ pe,
                                                 const float* __restrict__ qsc,
                                                 const float* __restrict__ ksc,
                                                 u16* __restrict__ Qr,
                                                 u16* __restrict__ Kr) {
  int row = blockIdx.x;  // b*L + l
  int l = row & (Lc - 1);
  int b = row >> 11;
  int tid = threadIdx.x;
  int h = tid >> 4, s16 = tid & 15;
  int d0 = s16 * 8;
  const u16* qp = qkvb + (long)row * N3c + h * HDc + d0;
  uint4 qv = *(const uint4*)qp;
  uint4 kv = *(const uint4*)(qp + Dc);
  const u16* qu = (const u16*)&qv;
  const u16* ku = (const u16*)&kv;
  float q[8], k[8];
#pragma unroll
  for (int j = 0; j < 8; j++) {
    q[j] = bf2f(qu[j]);
    k[j] = bf2f(ku[j]);
  }
  float sq = 0.f, sk = 0.f;
#pragma unroll
  for (int j = 0; j < 8; j++) {
    sq += q[j] * q[j];
    sk += k[j] * k[j];
  }
#pragma unroll
  for (int m = 1; m < 16; m <<= 1) {
    sq += __shfl_xor(sq, m);
    sk += __shfl_xor(sk, m);
  }
  float rq = rsqrtf(sq * (1.f / HDc) + 1e-6f);
  float rk = rsqrtf(sk * (1.f / HDc) + 1e-6f);
  float qs8[8], ks8[8];
  *(float4*)&qs8[0] = *(const float4*)(qsc + d0);
  *(float4*)&qs8[4] = *(const float4*)(qsc + d0 + 4);
  *(float4*)&ks8[0] = *(const float4*)(ksc + d0);
  *(float4*)&ks8[4] = *(const float4*)(ksc + d0 + 4);
#pragma unroll
  for (int j = 0; j < 8; j++) {
    q[j] *= rq * qs8[j];
    k[j] *= rk * ks8[j];
  }
  float e[16];
  const float* pep = pe + (long)l * 256 + s16 * 16;
#pragma unroll
  for (int j = 0; j < 4; j++) *(float4*)&e[j * 4] = *(const float4*)(pep + j * 4);
  float qo[8], ko[8];
#pragma unroll
  for (int p = 0; p < 4; p++) {
    float e00 = e[p * 4 + 0], e01 = e[p * 4 + 1];
    float e10 = e[p * 4 + 2], e11 = e[p * 4 + 3];
    qo[2 * p]     = e00 * q[2 * p] + e01 * q[2 * p + 1];
    qo[2 * p + 1] = e10 * q[2 * p] + e11 * q[2 * p + 1];
    ko[2 * p]     = e00 * k[2 * p] + e01 * k[2 * p + 1];
    ko[2 * p + 1] = e10 * k[2 * p] + e11 * k[2 * p + 1];
  }
  constexpr float RS = 0.08838834764831845f;  // 1/sqrt(128)
  uint4 oq, ok;
  oq.x = f2bf(qo[0] * RS) | ((unsigned)f2bf(qo[1] * RS) << 16);
  oq.y = f2bf(qo[2] * RS) | ((unsigned)f2bf(qo[3] * RS) << 16);
  oq.z = f2bf(qo[4] * RS) | ((unsigned)f2bf(qo[5] * RS) << 16);
  oq.w = f2bf(qo[6] * RS) | ((unsigned)f2bf(qo[7] * RS) << 16);
  ok.x = f2bf(ko[0]) | ((unsigned)f2bf(ko[1]) << 16);
  ok.y = f2bf(ko[2]) | ((unsigned)f2bf(ko[3]) << 16);
  ok.z = f2bf(ko[4]) | ((unsigned)f2bf(ko[5]) << 16);
  ok.w = f2bf(ko[6]) | ((unsigned)f2bf(ko[7]) << 16);
  long o = (((long)(b * Hc + h)) * Lc + l) * HDc + d0;
  *(uint4*)(Qr + o) = oq;
  *(uint4*)(Kr + o) = ok;
}

// ---------------- flash attention v6: R2 structure + XCD swizzle ----------------
// 64-row Q tiles, Q staged via lds-dma then regs, 48KB LDS, 3 blk/CU.
// XCD swizzle: bh = (bx&7)|((bx>>8)<<3), lt = (bx>>3)&31 -> one bh per XCD.
__global__ __launch_bounds__(256, 3) void k_attn(const u16* __restrict__ Qr,
                                                 const u16* __restrict__ Kr,
                                                 const u16* __restrict__ Vt,
                                                 u16* __restrict__ Ao) {
  __shared__ u16 smem[24576];  // 48 KB
  u16* sQ = smem;              // [64][128] staging; reused as sP [64][64] (8KB)
  u16* sK = smem + 8192;       // [64][128] 16KB; epilogue: red
  u16* sV = smem + 16384;      // [128][64] 16KB; epilogue: rsum
  u16* sP = sQ;
  int bx = blockIdx.x;
  int bh = (bx & 7) | ((bx >> 8) << 3);
  int lt = (bx >> 3) & 31;
  const u16* Qg = Qr + ((long)bh * Lc + lt * 64) * HDc;
  const u16* Kg = Kr + (long)bh * Lc * HDc;
  const u16* Vg = Vt + (long)bh * HDc * Lc;
  int tid = threadIdx.x, w = tid >> 6, lane = tid & 63;
  int quad = lane >> 4, l15 = lane & 15;
  int wsl = w >> 1, wsm = w & 1;  // S-phase wave grid: l x m
  int wd = w >> 1, wl2 = w & 1;   // PV-phase wave grid: d x l

  // ---- stage Q once (coalesced lds-dma), pull fragments into registers ----
#pragma unroll
  for (int i = 0; i < 4; i++) {
    int r = i * 16 + w * 4 + quad;
    int gch = l15 ^ (r & 15);
    load16(Qg + (long)r * HDc + gch * 8, sQ + (i * 16 + w * 4) * 128);
  }
  __syncthreads();
  bf16x8 qf[2][4];
#pragma unroll
  for (int mi = 0; mi < 2; mi++) {
    int l = wsl * 32 + mi * 16 + l15;
#pragma unroll
    for (int kk = 0; kk < 4; kk++)
      qf[mi][kk] = *(const bf16x8*)&sQ[l * 128 + (((kk * 4 + quad) ^ l15) << 3)];
  }

  f32x4 o[4][2] = {};
  float rs[8] = {};
  for (int t = 0; t < 32; t++) {
    int m0 = t * 64;
    __syncthreads();  // A: prev PV done reading sP/sV; Q frags read (t=0)
#pragma unroll
    for (int i = 0; i < 4; i++) {
      int r = i * 16 + w * 4 + quad;
      int gch = l15 ^ (r & 15);
      load16(Kg + ((long)(m0 + r)) * HDc + gch * 8, sK + (i * 16 + w * 4) * 128);
    }
#pragma unroll
    for (int i = 0; i < 4; i++) {
      int r = i * 32 + w * 8 + (lane >> 3);
      int gch = (lane & 7) ^ (r & 7);
      load16(Vg + (long)r * Lc + m0 + gch * 8, sV + (i * 32 + w * 8) * 64);
    }
    __syncthreads();  // B: staged
    // S = Q K^T  (64 l x 64 m; per wave 32x32 -> mi2 x ni2)
    f32x4 s[2][2] = {};
#pragma unroll
    for (int kk = 0; kk < 4; kk++) {
      bf16x8 bk[2];
#pragma unroll
      for (int ni = 0; ni < 2; ni++) {
        int m = wsm * 32 + ni * 16 + l15;
        bk[ni] = *(const bf16x8*)&sK[m * 128 + (((kk * 4 + quad) ^ l15) << 3)];
      }
#pragma unroll
      for (int mi = 0; mi < 2; mi++)
#pragma unroll
        for (int ni = 0; ni < 2; ni++)
          s[mi][ni] =
              __builtin_amdgcn_mfma_f32_16x16x32_bf16(qf[mi][kk], bk[ni], s[mi][ni], 0, 0, 0);
    }
    // exp + pack P into sP[l][m] (swizzled), accumulate row sums
#pragma unroll
    for (int mi = 0; mi < 2; mi++)
#pragma unroll
      for (int ni = 0; ni < 2; ni++) {
        int pc = wsm * 32 + ni * 16 + l15;
#pragma unroll
        for (int r = 0; r < 4; r++) {
          int pr = wsl * 32 + mi * 16 + quad * 4 + r;
          float p = __expf(s[mi][ni][r]);
          rs[mi * 4 + r] += p;
          unsigned u = __builtin_bit_cast(unsigned, p) + 0x8000u;
          sP[pr * 64 + ((((pc >> 3) ^ (pr & 7)) << 3) | (pc & 7))] = (u16)(u >> 16);
        }
      }
    __syncthreads();  // D: P visible
    // O^T += V^T P^T  (128 d x 64 l; per wave 64d x 32l -> mi4 x ni2)
#pragma unroll
    for (int kk = 0; kk < 2; kk++) {
      bf16x8 av[4], bp[2];
#pragma unroll
      for (int mi = 0; mi < 4; mi++) {
        int d = wd * 64 + mi * 16 + l15;
        av[mi] = *(const bf16x8*)&sV[d * 64 + (((kk * 4 + quad) ^ (d & 7)) << 3)];
      }
#pragma unroll
      for (int ni = 0; ni < 2; ni++) {
        int l = wl2 * 32 + ni * 16 + l15;
        bp[ni] = *(const bf16x8*)&sP[l * 64 + (((kk * 4 + quad) ^ (l & 7)) << 3)];
      }
#pragma unroll
      for (int mi = 0; mi < 4; mi++)
#pragma unroll
        for (int ni = 0; ni < 2; ni++)
          o[mi][ni] =
              __builtin_amdgcn_mfma_f32_16x16x32_bf16(av[mi], bp[ni], o[mi][ni], 0, 0, 0);
    }
  }
  // ---- epilogue: reduce row sums, scale, store O (b64 packed) ----
  __syncthreads();
  float* red  = (float*)sK;  // [64][33]
  float* rsum = (float*)sV;  // [64]
#pragma unroll
  for (int mi = 0; mi < 2; mi++)
#pragma unroll
    for (int r = 0; r < 4; r++) {
      int l = wsl * 32 + mi * 16 + quad * 4 + r;
      red[l * 33 + wsm * 16 + l15] = rs[mi * 4 + r];
    }
  __syncthreads();
  if (tid < 64) {
    float a = 0.f;
#pragma unroll
    for (int j = 0; j < 32; j++) a += red[tid * 33 + j];
    rsum[tid] = a;
  }
  __syncthreads();
  int b = bh >> 4, h = bh & 15;
#pragma unroll
  for (int ni = 0; ni < 2; ni++) {
    int l = wl2 * 32 + ni * 16 + l15;
    float inv = 1.f / rsum[l];
    long rowb = ((long)(b * Lc + lt * 64 + l)) * Dc + h * HDc;
#pragma unroll
    for (int mi = 0; mi < 4; mi++) {
      int d = wd * 64 + mi * 16 + quad * 4;
      ushort4 pk;
      pk.x = f2bf(o[mi][ni][0] * inv);
      pk.y = f2bf(o[mi][ni][1] * inv);
      pk.z = f2bf(o[mi][ni][2] * inv);
      pk.w = f2bf(o[mi][ni][3] * inv);
      *(ushort4*)(Ao + rowb + d) = pk;
    }
  }
}

extern "C" void kernel_launch(void* const* d_in, const int* in_sizes, int n_in,
                              void* d_out, int out_size, void* d_ws, size_t ws_size,
                              hipStream_t stream) {
  const float* x      = (const float*)d_in[0];
  const float* pe     = (const float*)d_in[1];
  const float* w_qkv  = (const float*)d_in[2];
  const float* w_proj = (const float*)d_in[3];
  const float* qs     = (const float*)d_in[4];
  const float* ks     = (const float*)d_in[5];
  float* out = (float*)d_out;
  char* ws = (char*)d_ws;

  u16* xb    = (u16*)(ws);                  //  16.8 MB  x bf16 [4096][2048]
  u16* wqkvT = (u16*)(ws + 16777216);       //  25.2 MB  [6144][2048]
  u16* wpT   = (u16*)(ws + 41943040);       //   8.4 MB  [2048][2048]
  u16* qkvb  = (u16*)(ws + 50331648);       //  50.3 MB  [4096][6144] bf16
  u16* Qr    = (u16*)(ws + 100663296);      //  16.8 MB  [B][H][L][HD]
  u16* Kr    = (u16*)(ws + 117440512);      //  16.8 MB
  u16* Vtw   = (u16*)(ws + 134217728);      //  16.8 MB  [B][H][HD][L]
  u16* Ao    = (u16*)(ws + 150994944);      //  16.8 MB  [4096][2048] bf16

  k_prep<<<5120, 256, 0, stream>>>(x, w_qkv, w_proj, xb, wqkvT, wpT);
  k_gemm<u16><<<32 * 48, 256, 0, stream>>>(xb, wqkvT, qkvb, Mc, N3c, Dc);
  k_rmsrope<<<Mc, 256, 0, stream>>>(qkvb, pe, qs, ks, Qr, Kr);
  k_vtrans<<<dim3(16, 32), 256, 0, stream>>>(qkvb, Vtw);
  k_attn<<<32 * 32, 256, 0, stream>>>(Qr, Kr, Vtw, Ao);
  k_gemm<float><<<32 * 16, 256, 0, stream>>>(Ao, wpT, out, Mc, Dc, Dc);
}